// Round 8
// baseline (333.508 us; speedup 1.0000x reference)
//
#include <hip/hip_runtime.h>
#include <hip/hip_bf16.h>

// Causal flash attention, B=4 H=16 S=2048 DK=DV=128, fp32 in/out, bf16 MFMA compute.
// R9: single-barrier pipeline. R8 still had TWO barriers/tile with the V-write +
// lgkm drain trapped between them (V single-buffered) -- the classic 2-phase
// stall (m233). Now BOTH K and V are double-buffered: iteration t writes tile
// t+1 (loaded at t-1) into buf^1, issues global loads for t+2, computes from
// buf, then ONE lgkm drain + s_barrier. V-writes and HBM latency ride under
// compute; vmcnt never drained in-loop (counted waits at the writes only).
// Everything else identical to R8: 8-wave 512-thr blocks, BM=256 (32 q/wave),
// swapped QK^T + in-register P transpose (cvt_pk + permlane32/16_swap),
// per-wave early-exit above the diagonal, LPT + XCD-pinned dispatch.
// LDS: 2*64*136*2 + 2*128*72*2 = 71680 B.

#define S_LEN 2048
#define DKC   128
#define DVC   128
#define BM    256   // q rows per block (32 per wave, 8 waves)
#define BN    64
#define KPAD  136   // K LDS row stride (bf16): 272B -> b128-aligned reads, 2-way banks
#define VPAD  72    // Vt LDS row stride:      144B -> b128-aligned reads, 2-way banks

typedef __bf16 bf16;
typedef bf16  bf16x4 __attribute__((ext_vector_type(4)));
typedef bf16  bf16x8 __attribute__((ext_vector_type(8)));
typedef float f32x4  __attribute__((ext_vector_type(4)));
typedef unsigned int u32;
typedef u32 u32x4 __attribute__((ext_vector_type(4)));

__global__ __launch_bounds__(512, 2)
void fa_kernel(const float* __restrict__ Q, const float* __restrict__ K,
               const float* __restrict__ V, float* __restrict__ O) {
  __shared__ bf16 Klds[2][BN][KPAD];     // double-buffered [key][d]
  __shared__ bf16 Vlds[2][DVC][VPAD];    // double-buffered, transposed [dv][key]

  const int tid  = threadIdx.x;
  const int w    = tid >> 6;             // 0..7
  const int lane = tid & 63;
  const int quad = lane >> 4;
  const int l16  = lane & 15;

  // XCD pinning (lin%8) + heavy-first (LPT) q-tile order within each bh group.
  const int lin = blockIdx.x;            // 0..511
  const int xcd = lin & 7;
  const int idx = lin >> 3;              // 0..63
  const int qt  = 7 - (idx & 7);         // 7..0, heavy first
  const int bh  = xcd + 8 * (idx >> 3);  // 0..63

  const int q0 = qt * BM;
  const size_t base = (size_t)bh * S_LEN * DKC;
  const float* Qp = Q + base;
  const float* Kp = K + base;
  const float* Vp = V + base;
  float*       Op = O + base;

  const float SCALE2 = 0.08838834764831845f * 1.4426950408889634f; // 1/sqrt(128)*log2e

  // ---- Q fragments, 2 groups of 16 rows (B-layout for swapped QK^T:
  //      lane holds Q[q=l16][k=quad*8+j], which is B[k][q] with col=q=l16) ----
  bf16x8 qf[2][4];
#pragma unroll
  for (int g = 0; g < 2; ++g) {
    const float* qrow = Qp + (size_t)(q0 + w * 32 + g * 16 + l16) * DKC;
#pragma unroll
    for (int c = 0; c < 4; ++c) {
      const float* pq = qrow + c * 32 + quad * 8;
      float4 x = *(const float4*)pq;
      float4 y = *(const float4*)(pq + 4);
      bf16x8 f;
      f[0] = (bf16)(x.x * SCALE2); f[1] = (bf16)(x.y * SCALE2);
      f[2] = (bf16)(x.z * SCALE2); f[3] = (bf16)(x.w * SCALE2);
      f[4] = (bf16)(y.x * SCALE2); f[5] = (bf16)(y.y * SCALE2);
      f[6] = (bf16)(y.z * SCALE2); f[7] = (bf16)(y.w * SCALE2);
      qf[g][c] = f;
    }
  }

  f32x4 oacc[2][8];
#pragma unroll
  for (int g = 0; g < 2; ++g)
#pragma unroll
    for (int n = 0; n < 8; ++n)
#pragma unroll
      for (int r = 0; r < 4; ++r) oacc[g][n][r] = 0.0f;
  float lsum[2] = {0.0f, 0.0f};   // per-lane denominator for q = l16 (per g-group)

  // staging addresses (512 threads: 4 K loads + 4 V loads each)
  const int krow = tid >> 5;          // 0..15 (+ i*16)
  const int kcol = (tid & 31) * 4;    // 0..124
  const int vk   = tid & 31;          // + 32*(i&1)
  const int vd   = tid >> 5;          // 0..15 (+ 16*(i>>1)) -> d/4 index

  const int ntiles = 4 * qt + 4;      // >= 4

  float4 kx[4], vx[4];

  // ---- prologue: tile 0 -> regs -> LDS[0]; tile 1 -> regs; one barrier ----
#pragma unroll
  for (int i = 0; i < 4; ++i)
    kx[i] = *(const float4*)(Kp + (size_t)(krow + i * 16) * DKC + kcol);
#pragma unroll
  for (int i = 0; i < 4; ++i) {
    int k  = vk + 32 * (i & 1);
    int d4 = (vd + 16 * (i >> 1)) * 4;
    vx[i] = *(const float4*)(Vp + (size_t)k * DVC + d4);
  }
#pragma unroll
  for (int i = 0; i < 4; ++i) {
    bf16x4 k4;
    k4[0] = (bf16)kx[i].x; k4[1] = (bf16)kx[i].y;
    k4[2] = (bf16)kx[i].z; k4[3] = (bf16)kx[i].w;
    *(bf16x4*)&Klds[0][krow + i * 16][kcol] = k4;
  }
#pragma unroll
  for (int i = 0; i < 4; ++i) {
    int k  = vk + 32 * (i & 1);
    int d4 = (vd + 16 * (i >> 1)) * 4;
    Vlds[0][d4 + 0][k] = (bf16)vx[i].x;
    Vlds[0][d4 + 1][k] = (bf16)vx[i].y;
    Vlds[0][d4 + 2][k] = (bf16)vx[i].z;
    Vlds[0][d4 + 3][k] = (bf16)vx[i].w;
  }
#pragma unroll
  for (int i = 0; i < 4; ++i)
    kx[i] = *(const float4*)(Kp + (size_t)(BN + krow + i * 16) * DKC + kcol);
#pragma unroll
  for (int i = 0; i < 4; ++i) {
    int k  = vk + 32 * (i & 1);
    int d4 = (vd + 16 * (i >> 1)) * 4;
    vx[i] = *(const float4*)(Vp + (size_t)(BN + k) * DVC + d4);
  }
  asm volatile("s_waitcnt lgkmcnt(0)\n\ts_barrier" ::: "memory");

  for (int t = 0; t < ntiles; ++t) {
    const int buf = t & 1;
    const int kvb = t * BN;
    // wave-local: does this wave's 32-row band still need tile t?
    const bool active    = (kvb <= q0 + w * 32 + 31);
    const bool need_mask = active && (kvb + BN - 1 > q0 + w * 32);

    // ---- write tile t+1 (regs, loaded at t-1) into buf^1. Safe: the barrier
    //      ending t-1 guaranteed all waves finished READING buf^1. Counted
    //      vmcnt waits (compiler) cover the kx/vx arrivals; one tile of
    //      latency already elapsed. ----
    if (t + 1 < ntiles) {
#pragma unroll
      for (int i = 0; i < 4; ++i) {
        bf16x4 k4;
        k4[0] = (bf16)kx[i].x; k4[1] = (bf16)kx[i].y;
        k4[2] = (bf16)kx[i].z; k4[3] = (bf16)kx[i].w;
        *(bf16x4*)&Klds[buf ^ 1][krow + i * 16][kcol] = k4;
      }
#pragma unroll
      for (int i = 0; i < 4; ++i) {
        int k  = vk + 32 * (i & 1);
        int d4 = (vd + 16 * (i >> 1)) * 4;
        Vlds[buf ^ 1][d4 + 0][k] = (bf16)vx[i].x;
        Vlds[buf ^ 1][d4 + 1][k] = (bf16)vx[i].y;
        Vlds[buf ^ 1][d4 + 2][k] = (bf16)vx[i].z;
        Vlds[buf ^ 1][d4 + 3][k] = (bf16)vx[i].w;
      }
    }
    // ---- issue global loads for tile t+2 (latency hides under compute;
    //      vmcnt never drained in-loop) ----
    if (t + 2 < ntiles) {
      const int kvb2 = kvb + 2 * BN;
#pragma unroll
      for (int i = 0; i < 4; ++i)
        kx[i] = *(const float4*)(Kp + (size_t)(kvb2 + krow + i * 16) * DKC + kcol);
#pragma unroll
      for (int i = 0; i < 4; ++i) {
        int k  = vk + 32 * (i & 1);
        int d4 = (vd + 16 * (i >> 1)) * 4;
        vx[i] = *(const float4*)(Vp + (size_t)(kvb2 + k) * DVC + d4);
      }
    }

    if (active) {
      // ---- S^T = K Q^T (swapped): per n-subtile, col=q=l16, row=key=quad*4+r.
      //      Fused mask + exp2 + denominator + bf16 pack (sacc lives 8 regs). ----
      u32 W[2][4][2];   // packed bf16 P: [g][n][lo/hi], quad holds keys quad*4+0..3
#pragma unroll
      for (int n = 0; n < 4; ++n) {
        f32x4 sacc[2];
#pragma unroll
        for (int g = 0; g < 2; ++g)
#pragma unroll
          for (int r = 0; r < 4; ++r) sacc[g][r] = 0.0f;
#pragma unroll
        for (int c = 0; c < 4; ++c) {
          bf16x8 kf = *(const bf16x8*)&Klds[buf][n * 16 + l16][c * 32 + quad * 8];
          sacc[0] = __builtin_amdgcn_mfma_f32_16x16x32_bf16(kf, qf[0][c], sacc[0], 0, 0, 0);
          sacc[1] = __builtin_amdgcn_mfma_f32_16x16x32_bf16(kf, qf[1][c], sacc[1], 0, 0, 0);
        }
        if (need_mask) {
          const int kg = kvb + n * 16 + quad * 4;
#pragma unroll
          for (int g = 0; g < 2; ++g) {
            const int qg = q0 + w * 32 + g * 16 + l16;
#pragma unroll
            for (int r = 0; r < 4; ++r)
              if (kg + r > qg) sacc[g][r] = -1e30f;  // exp2 -> 0
          }
        }
#pragma unroll
        for (int g = 0; g < 2; ++g) {
          float p0 = exp2f(sacc[g][0]);
          float p1 = exp2f(sacc[g][1]);
          float p2 = exp2f(sacc[g][2]);
          float p3 = exp2f(sacc[g][3]);
          lsum[g] += (p0 + p1) + (p2 + p3);
          asm("v_cvt_pk_bf16_f32 %0, %1, %2" : "=v"(W[g][n][0]) : "v"(p0), "v"(p1));
          asm("v_cvt_pk_bf16_f32 %0, %1, %2" : "=v"(W[g][n][1]) : "v"(p2), "v"(p3));
        }
      }

      // ---- P: C-layout -> A-layout IN REGISTERS (no LDS round-trip).
      //  permlane32_swap: P0'=[P0.r0,P0.r1,P1.r0,P1.r1], P1'=[P0.r2,P0.r3,P1.r2,P1.r3]
      //  permlane16_swap: E=[P0.r0,P0.r2,P1.r0,P1.r2], Od=[P0.r1,P0.r3,P1.r1,P1.r3]
      //  E/Od are exactly A-frag dwords {0,1}/{2,3}. ----
#pragma unroll
      for (int c = 0; c < 2; ++c) {
        bf16x8 pf[2];
#pragma unroll
        for (int g = 0; g < 2; ++g) {
          u32x4 pw;
#pragma unroll
          for (int h = 0; h < 2; ++h) {
            u32 pa = W[g][2 * c][h], pb = W[g][2 * c + 1][h];
            asm("v_permlane32_swap_b32 %0, %1" : "+v"(pa), "+v"(pb));
            asm("v_permlane16_swap_b32 %0, %1" : "+v"(pa), "+v"(pb));
            pw[h]     = pa;   // E  -> dwords 0 (lo) / 1 (hi)
            pw[2 + h] = pb;   // Od -> dwords 2 (lo) / 3 (hi)
          }
          pf[g] = __builtin_bit_cast(bf16x8, pw);
        }
        // ---- O += P V: each vf read feeds BOTH q-groups ----
#pragma unroll
        for (int n = 0; n < 8; ++n) {
          bf16x8 vf = *(const bf16x8*)&Vlds[buf][n * 16 + l16][c * 32 + quad * 8];
          oacc[0][n] = __builtin_amdgcn_mfma_f32_16x16x32_bf16(pf[0], vf, oacc[0][n], 0, 0, 0);
          oacc[1][n] = __builtin_amdgcn_mfma_f32_16x16x32_bf16(pf[1], vf, oacc[1][n], 0, 0, 0);
        }
      }
    }

    // ---- ONE barrier per tile: my t+1 writes are visible before anyone reads
    //      them at t+1, and everyone is done reading buf before it's
    //      overwritten at t+1. lgkm-only drain (vmcnt prefetch survives). ----
    asm volatile("s_waitcnt lgkmcnt(0)\n\ts_barrier" ::: "memory");
  }

  // ---- epilogue: lsum holds per-lane partial for q=l16; reduce across quads,
  //      gather each output row's denominator, normalize, store ----
#pragma unroll
  for (int g = 0; g < 2; ++g) {
    float s = lsum[g];
    s += __shfl_xor(s, 16);
    s += __shfl_xor(s, 32);         // every lane: full denom for q = its l16
    float linv[4];
#pragma unroll
    for (int r = 0; r < 4; ++r)
      linv[r] = 1.0f / __shfl(s, quad * 4 + r);  // oacc row q = quad*4+r
#pragma unroll
    for (int n = 0; n < 8; ++n) {
#pragma unroll
      for (int r = 0; r < 4; ++r) {
        int qg = q0 + w * 32 + g * 16 + quad * 4 + r;
        Op[(size_t)qg * DVC + n * 16 + l16] = oacc[g][n][r] * linv[r];
      }
    }
  }
}

extern "C" void kernel_launch(void* const* d_in, const int* in_sizes, int n_in,
                              void* d_out, int out_size, void* d_ws, size_t ws_size,
                              hipStream_t stream) {
  const float* Q = (const float*)d_in[0];
  const float* K = (const float*)d_in[1];
  const float* V = (const float*)d_in[2];
  // d_in[3] is the causal tril mask; causality is applied analytically.
  float* O = (float*)d_out;
  dim3 grid(512);   // 64 bh * 8 q-tiles (BM=256), XCD-pinned, heavy-first (LPT)
  fa_kernel<<<grid, 512, 0, stream>>>(Q, K, V, O);
}